// Round 6
// baseline (220.201 us; speedup 1.0000x reference)
//
#include <hip/hip_runtime.h>

// Banded stereo cost volume via MFMA, all 3 scales in ONE launch.
// cost[j,h,x] = sum_c L[c,h,x]*R[c,h,x-j], 0 if x<j. C=32.
//
// Round-10: fix round-9's two counter-diagnosed regressions, MFMA core kept.
// (a) WRITE_SIZE 358MB vs 115 ideal (3.1x): per-wave epilogue stored 128-B
//     row segments (8 lanes x 16B per j-row per inst) -> L2->HBM granule
//     RMW amplification (history rule: need >=256B, best 512B per 32-lane
//     group). Fix: block-cooperative epilogue -- waves deposit diagonal
//     tiles into a shared buffer per 16-j group, barrier, then all threads
//     store j-rows as 32-lane x 16B = 512B contiguous, nontemporal.
// (b) SQ_LDS_BANK_CONFLICT 8.9M: staging ds_write_b64 was ~16-way
//     conflicted; rows go 4 apart (256B stride = 0 mod 32 banks) and the
//     (row>>1)&3 XOR is constant within an inst. (row>>2)&3 = x4&3 varies
//     per lane -> 8-way. Read side uses matching XOR (stays conflict-free:
//     8 chunk positions x 4 banks = exact 32-bank cover).
// Epilogue buffer: transposed n-major tiles [n*16+m] so deposits are b128
// (acc regs m-contiguous: m = 4*kg+rr); mt stride 516 words (+4 pad) to
// spread banks across m-tiles in the gather.
// Core (unchanged from r9): per h, C[x,x'] = sum_c L[c,x]*R[c,x'] on the
// band 0<=x-x'<=D-1; K=32 = ONE v_mfma_f32_16x16x32_f16 per 16x16 tile.
// R staged zero-padded for x'<0 -> band zeros fall out of the matmul.
// Wave w: m-tiles 2w,2w+1; 13 n-tiles each; 26 mfma, 104 acc regs.

#define NBLK_TOTAL 1344

typedef float vf4 __attribute__((ext_vector_type(4)));
typedef float f32x4 __attribute__((ext_vector_type(4)));
typedef _Float16 h4 __attribute__((ext_vector_type(4)));
typedef _Float16 h8 __attribute__((ext_vector_type(8)));

__global__ __launch_bounds__(256, 3)
void cost_volume_fused(const float* __restrict__ L0, const float* __restrict__ R0,
                       const float* __restrict__ L1, const float* __restrict__ R1,
                       const float* __restrict__ L2, const float* __restrict__ R2,
                       float* __restrict__ out)
{
    // Staging: 448 rows (L: 0..127 = x-x0; R: 128..447 = x'-(x0-192)) x 64 B.
    __shared__ __align__(16) unsigned short St[448 * 32];   // 28 KB f16
    // Epilogue: 8 m-tiles x (2 slots x 256 + 4 pad) floats, shared by block.
    __shared__ __align__(16) float Ep[8 * 516];             // 16.1 KB

    const int id = blockIdx.x;
    const float* L; const float* R; float* o;
    int H, W, D, bx, h;
    if (id < 1024) {            // scale 0: H=256 W=512 D=192
        L = L0; R = R0; o = out;
        H = 256; W = 512; D = 192;
        bx = id & 3; h = id >> 2;
    } else if (id < 1280) {     // scale 1: H=128 W=256 D=96
        int r = id - 1024;
        L = L1; R = R1; o = out + (size_t)192 * 256 * 512;
        H = 128; W = 256; D = 96;
        bx = r & 1; h = r >> 1;
    } else {                    // scale 2: H=64 W=128 D=48
        int r = id - 1280;
        L = L2; R = R2; o = out + (size_t)192 * 256 * 512 + (size_t)96 * 128 * 256;
        H = 64; W = 128; D = 48;
        bx = 0; h = r;
    }

    const int x0 = bx * 128;
    const int t  = threadIdx.x;
    const int l  = t & 63;
    const int w_ = t >> 6;

    const size_t HW = (size_t)H * W;
    const float* Lb = L + (size_t)h * W;
    const float* Rb = R + (size_t)h * W;

    char* Sb = (char*)St;

    // ---- stage L: 256 items = (c4, x4); 4x4 reg transpose, f32 -> f16 ----
    {
        const int c0 = (t >> 5) * 4;
        const int x4 = t & 31;
        const float* gp = Lb + (size_t)c0 * HW + x0 + 4 * x4;
        vf4 v0 = *(const vf4*)(gp);
        vf4 v1 = *(const vf4*)(gp + HW);
        vf4 v2 = *(const vf4*)(gp + 2 * HW);
        vf4 v3 = *(const vf4*)(gp + 3 * HW);
        const int chk = (((c0 >> 3) ^ (x4 & 3)) << 4) | ((c0 & 7) << 1);
        #pragma unroll
        for (int xi = 0; xi < 4; ++xi) {
            int row = 4 * x4 + xi;
            h4 hv = { (_Float16)v0[xi], (_Float16)v1[xi],
                      (_Float16)v2[xi], (_Float16)v3[xi] };
            *(h4*)(Sb + row * 64 + chk) = hv;
        }
    }
    // ---- stage R: 640 items; x' = x0-192+4*x4; x'<0 rows = 0 ----
    #pragma unroll
    for (int k = 0; k < 3; ++k) {
        int idm = t + k * 256;
        if (idm < 640) {
            int c0 = (idm / 80) * 4;
            int x4 = idm - (idm / 80) * 80;
            int g = x0 - 192 + 4 * x4;
            vf4 v0 = (vf4)(0.f), v1 = (vf4)(0.f), v2 = (vf4)(0.f), v3 = (vf4)(0.f);
            if (g >= 0) {   // g+3 <= x0+127 <= W-1 always
                const float* gp = Rb + (size_t)c0 * HW + g;
                v0 = *(const vf4*)(gp);
                v1 = *(const vf4*)(gp + HW);
                v2 = *(const vf4*)(gp + 2 * HW);
                v3 = *(const vf4*)(gp + 3 * HW);
            }
            const int chk = (((c0 >> 3) ^ (x4 & 3)) << 4) | ((c0 & 7) << 1);
            #pragma unroll
            for (int xi = 0; xi < 4; ++xi) {
                int row = 128 + 4 * x4 + xi;   // (row>>2)&3 == x4&3 (128%4==0)
                h4 hv = { (_Float16)v0[xi], (_Float16)v1[xi],
                          (_Float16)v2[xi], (_Float16)v3[xi] };
                *(h4*)(Sb + row * 64 + chk) = hv;
            }
        }
    }
    __syncthreads();

    // ---- MFMA: wave w -> m-tiles q0=2w, q0+1; n-tiles q..q+12 each ----
    const int lm = l & 15;
    const int kg = l >> 4;
    const int q0 = 2 * w_;
    const int rsw = (lm >> 2) & 3;        // (row>>2)&3 for rows 16q+lm

    f32x4 acc0[13], acc1[13];
    #pragma unroll
    for (int i = 0; i < 13; ++i) { acc0[i] = (f32x4)(0.f); acc1[i] = (f32x4)(0.f); }

    const int rowA0 = 16 * q0 + lm;
    const int rowA1 = rowA0 + 16;
    h8 a0 = *(const h8*)(Sb + rowA0 * 64 + ((kg ^ rsw) << 4));
    h8 a1 = *(const h8*)(Sb + rowA1 * 64 + ((kg ^ rsw) << 4));

    #pragma unroll
    for (int nt = 0; nt <= 13; ++nt) {
        int rowB = 128 + 16 * (q0 + nt) + lm;
        h8 b = *(const h8*)(Sb + rowB * 64 + ((kg ^ rsw) << 4));
        if (nt <= 12)
            acc0[nt] = __builtin_amdgcn_mfma_f32_16x16x32_f16(a0, b, acc0[nt], 0, 0, 0);
        if (nt >= 1)
            acc1[nt - 1] = __builtin_amdgcn_mfma_f32_16x16x32_f16(a1, b, acc1[nt - 1], 0, 0, 0);
    }

    // ---- epilogue: block-cooperative sliding window over j-groups ----
    // jg uses tiles rel 12-jg (slot (12-jg)&1) and 11-jg (slot (11-jg)&1).
    // Deposit: wave w writes its tiles (m-tiles 2w, 2w+1) n-major so the
    // 4 acc components (m = 4kg+rr) form one b128: Ep[mt*516 + slot*256
    // + n*16 + m]. Gather+store: thread t -> j = 16jg+8r+(t>>5),
    // x = x0+4*(t&31)+i: 32 lanes x 16B = 512B contiguous per j-row.
    const int Dg = D >> 4;      // 12, 6, 3

    #pragma unroll 1
    for (int jg = 0; jg < 12; ++jg) {
        if (jg >= Dg) break;
        {   // deposit rel = 11-jg (and rel = 12 at jg==0)
            #pragma unroll
            for (int e = 0; e < 2; ++e) {
                int rel = (e == 0) ? (11 - jg) : 12;
                if (e == 1 && jg != 0) break;
                int slot = rel & 1;
                int b0 = (q0)     * 516 + slot * 256 + lm * 16 + 4 * kg;
                int b1 = (q0 + 1) * 516 + slot * 256 + lm * 16 + 4 * kg;
                *(f32x4*)&Ep[b0] = acc0[rel];
                *(f32x4*)&Ep[b1] = acc1[rel];
            }
        }
        __syncthreads();
        const int s12 = jg & 1;           // slot of rel 12-jg
        const int s11 = s12 ^ 1;          // slot of rel 11-jg
        #pragma unroll
        for (int r = 0; r < 2; ++r) {
            int jo = 8 * r + (t >> 5);
            int j  = 16 * jg + jo;
            int xs = 4 * (t & 31);
            int mt = xs >> 4;
            int mb = xs & 15;
            vf4 v;
            #pragma unroll
            for (int i = 0; i < 4; ++i) {
                int m = mb + i;                   // <= 15
                int slot = (m >= jo) ? s12 : s11;
                int n = (m - jo) & 15;
                v[i] = Ep[mt * 516 + slot * 256 + n * 16 + m];
            }
            float* p = o + ((size_t)j * H + h) * W + x0 + xs;
            __builtin_nontemporal_store(v, (vf4*)p);
        }
        if (jg + 1 < Dg) __syncthreads();   // protect slots before overwrite
    }
}

extern "C" void kernel_launch(void* const* d_in, const int* in_sizes, int n_in,
                              void* d_out, int out_size, void* d_ws, size_t ws_size,
                              hipStream_t stream)
{
    const float* L0 = (const float*)d_in[0];
    const float* R0 = (const float*)d_in[1];
    const float* L1 = (const float*)d_in[2];
    const float* R1 = (const float*)d_in[3];
    const float* L2 = (const float*)d_in[4];
    const float* R2 = (const float*)d_in[5];
    float* out = (float*)d_out;

    cost_volume_fused<<<dim3(NBLK_TOTAL), dim3(256), 0, stream>>>(
        L0, R0, L1, R1, L2, R2, out);
}

// Round 8
// 166.198 us; speedup vs baseline: 1.3249x; 1.3249x over previous
//
#include <hip/hip_runtime.h>

// Banded stereo cost volume via MFMA, all 3 scales in ONE launch.
// cost[j,h,x] = sum_c L[c,h,x]*R[c,h,x-j], 0 if x<j. C=32.
//
// Round-12 = round-11 resubmit (round-11 bench died with "container failed
// twice" -- infra error, no kernel diagnostics; source re-audited: LDS
// 52.3KB, all LDS/global indices in-bounds, barriers uniform, swizzle
// bijective).
//
// Round-11: kill the scratch spill. r5/r6 had VGPR_Count=68 with 104 regs
// of accumulators -> acc0[rel]/acc1[rel] runtime-indexed (rule #20) put the
// acc arrays in LOCAL MEMORY: every MFMA round-tripped scratch, +267 MB HBM
// write excess (382 vs 115 ideal), +39 MB fetch. Fix: epilogue is now a
// template<int DG> (12/6/3 per scale) with #pragma unroll and compile-time
// jg -> ALL acc indices static -> accs live in AGPRs. launch_bounds(256,2)
// gives the ~180 unified regs room (no forced spill).
// Also: staging row stride 64->80 B (breaks the 128B bank-cycle alias:
// write conflicts 8->4-way, frag-read bases spread 20*lm mod 32 over 8
// banks), and an XCD-chunked bijective block swizzle (1344 = 8*168) so
// same-h blocks (overlapping R windows) share one XCD's L2.
// Core (r9, numerically verified r5/r6): per h, C[x,x'] = sum_c L[c,x]*
// R[c,x'] on band 0<=x-x'<=D-1; K=32 = ONE v_mfma_f32_16x16x32_f16 per
// tile. R staged zero-padded for x'<0 -> band zeros fall out of the mm.
// Wave w: m-tiles 2w,2w+1; n-tiles q..q+12; 26 mfma, 104 acc regs.
// Epilogue (r6, verified): block-cooperative sliding window, 16-j groups,
// stores 32 lanes x 16B = 512B contiguous per j-row, nontemporal.

#define NBLK_TOTAL 1344
#define SRB 80          // staging row stride in BYTES (20 floats, 16B-aligned)

typedef float vf4 __attribute__((ext_vector_type(4)));
typedef float f32x4 __attribute__((ext_vector_type(4)));
typedef _Float16 h4 __attribute__((ext_vector_type(4)));
typedef _Float16 h8 __attribute__((ext_vector_type(8)));

template<int DG>
__device__ __forceinline__ void epilogue(const f32x4 (&acc0)[13], const f32x4 (&acc1)[13],
                                         float* __restrict__ Ep, float* __restrict__ o,
                                         int H, int W, int h, int x0,
                                         int t, int lm, int kg, int q0)
{
    // jg uses tiles rel 12-jg (slot (12-jg)&1) and 11-jg (slot (11-jg)&1).
    #pragma unroll
    for (int jg = 0; jg < DG; ++jg) {
        if (jg == 0) {   // compile-time folds
            int b0 = (q0)     * 516 + (12 & 1) * 256 + lm * 16 + 4 * kg;
            int b1 = (q0 + 1) * 516 + (12 & 1) * 256 + lm * 16 + 4 * kg;
            *(f32x4*)&Ep[b0] = acc0[12];
            *(f32x4*)&Ep[b1] = acc1[12];
        }
        {
            int b0 = (q0)     * 516 + ((11 - jg) & 1) * 256 + lm * 16 + 4 * kg;
            int b1 = (q0 + 1) * 516 + ((11 - jg) & 1) * 256 + lm * 16 + 4 * kg;
            *(f32x4*)&Ep[b0] = acc0[11 - jg];
            *(f32x4*)&Ep[b1] = acc1[11 - jg];
        }
        __syncthreads();
        const int s12 = jg & 1;           // slot of rel 12-jg
        const int s11 = s12 ^ 1;          // slot of rel 11-jg
        #pragma unroll
        for (int r = 0; r < 2; ++r) {
            int jo = 8 * r + (t >> 5);
            int j  = 16 * jg + jo;
            int xs = 4 * (t & 31);
            int mt = xs >> 4;
            int mb = xs & 15;
            vf4 v;
            #pragma unroll
            for (int i = 0; i < 4; ++i) {
                int m = mb + i;                   // <= 15
                int slot = (m >= jo) ? s12 : s11;
                int n = (m - jo) & 15;
                v[i] = Ep[mt * 516 + slot * 256 + n * 16 + m];
            }
            float* p = o + ((size_t)j * H + h) * W + x0 + xs;
            __builtin_nontemporal_store(v, (vf4*)p);
        }
        if (jg + 1 < DG) __syncthreads();   // protect slots before overwrite
    }
}

__global__ __launch_bounds__(256, 2)
void cost_volume_fused(const float* __restrict__ L0, const float* __restrict__ R0,
                       const float* __restrict__ L1, const float* __restrict__ R1,
                       const float* __restrict__ L2, const float* __restrict__ R2,
                       float* __restrict__ out)
{
    // Staging: 448 rows (L: 0..127 = x-x0; R: 128..447 = x'-(x0-192)),
    // 64 B payload per row, 80 B stride. 35 KB.
    __shared__ __align__(16) char St[448 * SRB];
    // Epilogue: 8 m-tiles x (2 slots x 256 + 4 pad) floats. 16.1 KB.
    __shared__ __align__(16) float Ep[8 * 516];

    // XCD-chunked bijective swizzle: 1344 = 8 * 168. Consecutive logical
    // ids (same h) land on one XCD -> R-window overlap shared in L2.
    const int id = (blockIdx.x & 7) * 168 + (blockIdx.x >> 3);

    const float* L; const float* R; float* o;
    int H, W, D, bx, h;
    if (id < 1024) {            // scale 0: H=256 W=512 D=192
        L = L0; R = R0; o = out;
        H = 256; W = 512; D = 192;
        bx = id & 3; h = id >> 2;
    } else if (id < 1280) {     // scale 1: H=128 W=256 D=96
        int r = id - 1024;
        L = L1; R = R1; o = out + (size_t)192 * 256 * 512;
        H = 128; W = 256; D = 96;
        bx = r & 1; h = r >> 1;
    } else {                    // scale 2: H=64 W=128 D=48
        int r = id - 1280;
        L = L2; R = R2; o = out + (size_t)192 * 256 * 512 + (size_t)96 * 128 * 256;
        H = 64; W = 128; D = 48;
        bx = 0; h = r;
    }

    const int x0 = bx * 128;
    const int t  = threadIdx.x;
    const int l  = t & 63;
    const int w_ = t >> 6;

    const size_t HW = (size_t)H * W;
    const float* Lb = L + (size_t)h * W;
    const float* Rb = R + (size_t)h * W;

    char* Sb = (char*)St;

    // ---- stage L: 256 items = (c4, x4); 4x4 reg transpose, f32 -> f16 ----
    {
        const int c0 = (t >> 5) * 4;
        const int x4 = t & 31;
        const float* gp = Lb + (size_t)c0 * HW + x0 + 4 * x4;
        vf4 v0 = *(const vf4*)(gp);
        vf4 v1 = *(const vf4*)(gp + HW);
        vf4 v2 = *(const vf4*)(gp + 2 * HW);
        vf4 v3 = *(const vf4*)(gp + 3 * HW);
        const int chk = (((c0 >> 3) ^ (x4 & 3)) << 4) | ((c0 & 7) << 1);
        #pragma unroll
        for (int xi = 0; xi < 4; ++xi) {
            int row = 4 * x4 + xi;            // (row>>2)&3 == x4&3
            h4 hv = { (_Float16)v0[xi], (_Float16)v1[xi],
                      (_Float16)v2[xi], (_Float16)v3[xi] };
            *(h4*)(Sb + row * SRB + chk) = hv;
        }
    }
    // ---- stage R: 640 items; x' = x0-192+4*x4; x'<0 rows = 0 ----
    #pragma unroll
    for (int k = 0; k < 3; ++k) {
        int idm = t + k * 256;
        if (idm < 640) {
            int c0 = (idm / 80) * 4;
            int x4 = idm - (idm / 80) * 80;
            int g = x0 - 192 + 4 * x4;
            vf4 v0 = (vf4)(0.f), v1 = (vf4)(0.f), v2 = (vf4)(0.f), v3 = (vf4)(0.f);
            if (g >= 0) {   // g+3 <= x0+127 <= W-1 always
                const float* gp = Rb + (size_t)c0 * HW + g;
                v0 = *(const vf4*)(gp);
                v1 = *(const vf4*)(gp + HW);
                v2 = *(const vf4*)(gp + 2 * HW);
                v3 = *(const vf4*)(gp + 3 * HW);
            }
            const int chk = (((c0 >> 3) ^ (x4 & 3)) << 4) | ((c0 & 7) << 1);
            #pragma unroll
            for (int xi = 0; xi < 4; ++xi) {
                int row = 128 + 4 * x4 + xi;   // (row>>2)&3 == x4&3 (128%4==0)
                h4 hv = { (_Float16)v0[xi], (_Float16)v1[xi],
                          (_Float16)v2[xi], (_Float16)v3[xi] };
                *(h4*)(Sb + row * SRB + chk) = hv;
            }
        }
    }
    __syncthreads();

    // ---- MFMA: wave w -> m-tiles q0=2w, q0+1; n-tiles q..q+12 each ----
    const int lm = l & 15;
    const int kg = l >> 4;
    const int q0 = 2 * w_;
    const int rsw = (lm >> 2) & 3;        // (row>>2)&3 for rows 16q+lm

    f32x4 acc0[13], acc1[13];
    #pragma unroll
    for (int i = 0; i < 13; ++i) { acc0[i] = (f32x4)(0.f); acc1[i] = (f32x4)(0.f); }

    const int rowA0 = 16 * q0 + lm;
    const int rowA1 = rowA0 + 16;
    h8 a0 = *(const h8*)(Sb + rowA0 * SRB + ((kg ^ rsw) << 4));
    h8 a1 = *(const h8*)(Sb + rowA1 * SRB + ((kg ^ rsw) << 4));

    #pragma unroll
    for (int nt = 0; nt <= 13; ++nt) {
        int rowB = 128 + 16 * (q0 + nt) + lm;
        h8 b = *(const h8*)(Sb + rowB * SRB + ((kg ^ rsw) << 4));
        if (nt <= 12)
            acc0[nt] = __builtin_amdgcn_mfma_f32_16x16x32_f16(a0, b, acc0[nt], 0, 0, 0);
        if (nt >= 1)
            acc1[nt - 1] = __builtin_amdgcn_mfma_f32_16x16x32_f16(a1, b, acc1[nt - 1], 0, 0, 0);
    }

    // ---- epilogue: compile-time DG per scale -> all acc indices static ----
    if (D == 192)      epilogue<12>(acc0, acc1, Ep, o, H, W, h, x0, t, lm, kg, q0);
    else if (D == 96)  epilogue<6>(acc0, acc1, Ep, o, H, W, h, x0, t, lm, kg, q0);
    else               epilogue<3>(acc0, acc1, Ep, o, H, W, h, x0, t, lm, kg, q0);
}

extern "C" void kernel_launch(void* const* d_in, const int* in_sizes, int n_in,
                              void* d_out, int out_size, void* d_ws, size_t ws_size,
                              hipStream_t stream)
{
    const float* L0 = (const float*)d_in[0];
    const float* R0 = (const float*)d_in[1];
    const float* L1 = (const float*)d_in[2];
    const float* R1 = (const float*)d_in[3];
    const float* L2 = (const float*)d_in[4];
    const float* R2 = (const float*)d_in[5];
    float* out = (float*)d_out;

    cost_volume_fused<<<dim3(NBLK_TOTAL), dim3(256), 0, stream>>>(
        L0, R0, L1, R1, L2, R2, out);
}